// Round 7
// baseline (117.231 us; speedup 1.0000x reference)
//
#include <hip/hip_runtime.h>

#define NBATCH 4096
#define SEQ 512
#define HID 5
#define NEMB 64

__device__ __forceinline__ float fexp2(float x){ return __builtin_amdgcn_exp2f(x); }
__device__ __forceinline__ float frcp(float x){ return __builtin_amdgcn_rcpf(x); }

// masked DPP: lanes selected by (rmask,bmask) get src permuted by CTRL, others keep old
#define DPP(old, src, CTRL, RMASK, BMASK) \
    __int_as_float(__builtin_amdgcn_update_dpp(__float_as_int(old), __float_as_int(src), (CTRL), (RMASK), (BMASK), false))
// quad_perm broadcast of quad-lane j to the whole quad (all lanes written)
#define DPPQ(v, j) __int_as_float(__builtin_amdgcn_update_dpp(0, __float_as_int(v), ((j) * 0x55), 0xF, 0xF, true))

// empirically pinned on this toolchain (r5 passed): row_shl:N -> lane i reads lane i+N,
// row_shr:N -> lane i reads lane i-N. wave_shl:1 -> lane i reads lane i+1.
#define ROW_SHL4  0x104
#define ROW_SHL8  0x108
#define ROW_SHR4  0x114
#define ROW_SHR8  0x118
#define WAVE_SHL1 0x130
#define BCAST15   0x142
#define QP3       0xFF   /* quad_perm(3,3,3,3) */

__global__ __launch_bounds__(64) void lstm_enc_kernel(
    const float* __restrict__ x_num, const int* __restrict__ x_cat,
    const float* __restrict__ embed, const float* __restrict__ W_ih,
    const float* __restrict__ W_hh, const float* __restrict__ b_ih,
    const float* __restrict__ b_hh, float* __restrict__ out)
{
    __shared__ float4 s_emb[NEMB];
    int tid = threadIdx.x;
    s_emb[tid] = ((const float4*)embed)[tid];
    __syncthreads();

    // 2 batch elements per wave, one per 32-lane half.
    // lane l (in half): quad q=l>>2 holds unit k=min(q,4); g=l&3 is the gate.
    // quads 4..7 all replicate unit 4 => row1 (lanes 16..31) uniformly carries h4.
    int half = tid >> 5;
    int l    = tid & 31;
    int b    = blockIdx.x * 2 + half;
    int k    = ((l >> 2) < HID) ? (l >> 2) : (HID - 1);
    int g    = l & 3;                       // 0:i 1:f 2:g 3:o
    bool st  = (l < 20) && (g == 0);        // storing lanes: l = 0,4,8,12,16

    const float L2E = 1.4426950408889634f;
    float s_  = (g == 2) ? (-2.0f * L2E) : (-L2E);
    float fm  = (g == 2) ? 2.0f : 1.0f;     // activation fixup: v = r*fm + fb
    float fb  = (g == 2) ? -1.0f : 0.0f;

    int row = g * HID + k;
    float wi_[5], wh_[5];
#pragma unroll
    for (int d = 0; d < 5; ++d) {
        wi_[d] = W_ih[row * 5 + d] * s_;
        wh_[d] = W_hh[row * 5 + d] * s_;
    }
    float bias = (b_ih[row] + b_hh[row]) * s_;

    const float4* xp = (const float4*)(x_num + (size_t)b * SEQ);
    const int4*   cp = (const int4*)(x_cat + (size_t)b * SEQ);
    float* outp = out + (size_t)b * SEQ * HID + k;

    float h = 0.f, c = 0.f;
    float hb0 = 0.f, hb1 = 0.f, hb2 = 0.f, hb3 = 0.f, hb4 = 0.f;

    float4 xf = xp[0];
    int4   cf = cp[0];
    float4 ec_[4];
    ec_[0] = s_emb[cf.x]; ec_[1] = s_emb[cf.y];
    ec_[2] = s_emb[cf.z]; ec_[3] = s_emb[cf.w];

    for (int t0 = 0; t0 < SEQ; t0 += 4) {
        int nidx = (t0 + 4 < SEQ) ? ((t0 >> 2) + 1) : 0;
        float4 xf_n = xp[nidx];
        int4   cf_n = cp[nidx];

        float xn_a[4] = {xf.x, xf.y, xf.z, xf.w};

        // off-chain: bias + x + emb part (one gate value per lane)
        float xa[4];
#pragma unroll
        for (int u = 0; u < 4; ++u) {
            float4 e = ec_[u];
            float a = fmaf(xn_a[u], wi_[0], bias);
            a = fmaf(e.x, wi_[1], a);
            a = fmaf(e.y, wi_[2], a);
            a = fmaf(e.z, wi_[3], a);
            a = fmaf(e.w, wi_[4], a);
            xa[u] = a;
        }

#pragma unroll
        for (int u = 0; u < 4; ++u) {
            // h-part: 5-FMA dot with broadcast h (per-lane gate row)
            float a = xa[u];
            a = fmaf(hb0, wh_[0], a);
            a = fmaf(hb1, wh_[1], a);
            a = fmaf(hb2, wh_[2], a);
            a = fmaf(hb3, wh_[3], a);
            a = fmaf(hb4, wh_[4], a);

            // ONE sigma per lane; tanh-gate lanes apply 2r-1 via per-lane consts
            float r = frcp(1.0f + fexp2(a));
            float v = fmaf(r, fm, fb);

            // gather i,f,g,o within the unit's quad (pure VALU)
            float ai = DPPQ(v, 0);
            float af = DPPQ(v, 1);
            float ag = DPPQ(v, 2);
            float ao = DPPQ(v, 3);

            // c,h computed redundantly on all lanes of the quad
            c = fmaf(af, c, ai * ag);
            float tc = fmaf(frcp(1.0f + fexp2(c * (-2.0f * L2E))), 2.0f, -1.0f);
            h = ao * tc;

            // ---- pure-VALU broadcast of h0..h4 to all 32 lanes of the half ----
            // h by quad (per half): [h0,h1,h2,h3,h4,h4,h4,h4]
            float s = DPP(h, h, WAVE_SHL1, 0xF, 0xF);   // lane15 <- lane16 (=h4); lane47 <- lane48
            // hb4: row1 already h4; fill row0 from lane15
            float b4 = DPP(h,  s,  QP3,      0x5, 0x8); // rows0,2 quad3 <- lane15 (h4)
            b4       = DPP(b4, b4, ROW_SHL4, 0x5, 0x4); // quad2 <- quad3
            b4       = DPP(b4, b4, ROW_SHL8, 0x5, 0x3); // quads0,1 <- quads2,3
            // hb0: h0 @ quad0
            float b0 = DPP(h,  h,  ROW_SHR4, 0x5, 0x2); // quad1 <- quad0
            b0       = DPP(b0, b0, ROW_SHR8, 0x5, 0xC); // quads2,3 <- quads0,1
            b0       = DPP(b0, b0, BCAST15,  0xA, 0xF); // row1 <- lane15 (h0)
            // hb1: h1 @ quad1
            float b1 = DPP(h,  h,  ROW_SHL4, 0x5, 0x1); // quad0 <- quad1
            b1       = DPP(b1, b1, ROW_SHR8, 0x5, 0xC); // quads2,3 <- quads0,1 (h1)
            b1       = DPP(b1, b1, BCAST15,  0xA, 0xF);
            // hb2: h2 @ quad2
            float b2 = DPP(h,  h,  ROW_SHR4, 0x5, 0x8); // quad3 <- quad2
            b2       = DPP(b2, b2, ROW_SHL8, 0x5, 0x3); // quads0,1 <- quads2,3 (h2)
            b2       = DPP(b2, b2, BCAST15,  0xA, 0xF);
            // hb3: h3 @ quad3
            float b3 = DPP(h,  h,  ROW_SHL4, 0x5, 0x4); // quad2 <- quad3 (h3)
            b3       = DPP(b3, b3, ROW_SHL8, 0x5, 0x3); // quads0,1 <- quads2,3 (h3)
            b3       = DPP(b3, b3, BCAST15,  0xA, 0xF); // lane15 = h3 (untouched) -> row1
            hb0 = b0; hb1 = b1; hb2 = b2; hb3 = b3; hb4 = b4;

            if (st) outp[(t0 + u) * HID] = h;
        }

        ec_[0] = s_emb[cf_n.x]; ec_[1] = s_emb[cf_n.y];
        ec_[2] = s_emb[cf_n.z]; ec_[3] = s_emb[cf_n.w];
        xf = xf_n;
    }

    if (st) {
        size_t base = (size_t)NBATCH * SEQ * HID;
        out[base + (size_t)b * HID + k] = h;                          // hT
        out[base + (size_t)NBATCH * HID + (size_t)b * HID + k] = c;   // cT
    }
}

extern "C" void kernel_launch(void* const* d_in, const int* in_sizes, int n_in,
                              void* d_out, int out_size, void* d_ws, size_t ws_size,
                              hipStream_t stream) {
    const float* x_num = (const float*)d_in[0];
    const int*   x_cat = (const int*)d_in[1];
    const float* embed = (const float*)d_in[2];
    const float* W_ih  = (const float*)d_in[3];
    const float* W_hh  = (const float*)d_in[4];
    const float* b_ih  = (const float*)d_in[5];
    const float* b_hh  = (const float*)d_in[6];
    float* out = (float*)d_out;

    dim3 grid(NBATCH / 2);   // 2048 blocks, 1 wave each -> 2 waves/SIMD
    dim3 block(64);
    hipLaunchKernelGGL(lstm_enc_kernel, grid, block, 0, stream,
                       x_num, x_cat, embed, W_ih, W_hh, b_ih, b_hh, out);
}